// Round 2
// baseline (522.737 us; speedup 1.0000x reference)
//
#include <hip/hip_runtime.h>

// ReluTransformer backsubstitution, v2: column-stripe with register-resident
// scales. w_lb/w_ub are [N+1,N+1] = diag block + bias last column + e_{N+1}
// last row, so:
//   new_lb[r,j<N] = max(lb,0)*dl[j] + min(lb,0)*du[j]
//   new_ub[r,j<N] = max(ub,0)*du[j] + min(ub,0)*dl[j]
//   new_lb[r,N]   = sum_j max(lb,0)*bl[j] + min(lb,0)*bu[j]   (incl j=N term)
//   new_ub[r,N]   = sum_j max(ub,0)*bu[j] + min(ub,0)*bl[j]
//
// Each 512-thread block owns 8 rows; each thread owns 8 fixed columns whose
// dl/du/bl/bu live in registers (loaded once, reused 8x). Plain dword
// loads/stores: perfectly coalesced, no stride-4097 alignment games.

#define N_IN   4096
#define NCOLS  4097
#define NROWS  8192
#define PAD    4104          // ws array stride (floats)
#define BLK    512
#define CPT    8             // columns per thread = N_IN / BLK
#define RPB    8             // rows per block

// ws: 4 arrays of PAD floats: 0=dl 1=du 2=bl 3=bu, index j in [0, NCOLS)
__global__ void extract_scales(const float* __restrict__ w_lb,
                               const float* __restrict__ w_ub,
                               float* __restrict__ ws) {
    int j = blockIdx.x * blockDim.x + threadIdx.x;
    if (j >= NCOLS) return;
    size_t row = (size_t)j * NCOLS;
    ws[0 * PAD + j] = w_lb[row + j];        // dl (j==N: w[N,N]=1)
    ws[1 * PAD + j] = w_ub[row + j];        // du
    ws[2 * PAD + j] = w_lb[row + N_IN];     // bl (j==N: 1)
    ws[3 * PAD + j] = w_ub[row + N_IN];     // bu
}

__global__ __launch_bounds__(BLK, 4) void backsub_rows(
        const float* __restrict__ lb, const float* __restrict__ ub,
        const float* __restrict__ ws, float* __restrict__ out) {
    const int tid = threadIdx.x;
    const int rowBase = blockIdx.x * RPB;

    // scales for this thread's 8 columns: col = c*BLK + tid
    float dl[CPT], du[CPT], bl[CPT], bu[CPT];
#pragma unroll
    for (int c = 0; c < CPT; ++c) {
        int col = c * BLK + tid;
        dl[c] = ws[0 * PAD + col];
        du[c] = ws[1 * PAD + col];
        bl[c] = ws[2 * PAD + col];
        bu[c] = ws[3 * PAD + col];
    }
    // thread 0 also handles the j = N_IN input element (bias-only contribution)
    float blN = 0.f, buN = 0.f;
    if (tid == 0) { blN = ws[2 * PAD + N_IN]; buN = ws[3 * PAD + N_IN]; }

    float alb[RPB], aub[RPB];
#pragma unroll
    for (int i = 0; i < RPB; ++i) { alb[i] = 0.f; aub[i] = 0.f; }

    const float* lb_row  = lb + (size_t)rowBase * NCOLS;
    const float* ub_row  = ub + (size_t)rowBase * NCOLS;
    float* olb_row = out + (size_t)rowBase * NCOLS;
    float* oub_row = out + (size_t)NROWS * NCOLS + (size_t)rowBase * NCOLS;

    for (int i = 0; i < RPB; ++i) {
#pragma unroll
        for (int c = 0; c < CPT; ++c) {
            const int col = c * BLK + tid;
            float x = lb_row[col];
            float y = ub_row[col];
            float px = fmaxf(x, 0.f), mx = fminf(x, 0.f);
            float py = fmaxf(y, 0.f), my = fminf(y, 0.f);
            olb_row[col] = px * dl[c] + mx * du[c];
            oub_row[col] = py * du[c] + my * dl[c];
            alb[i] = fmaf(px, bl[c], fmaf(mx, bu[c], alb[i]));
            aub[i] = fmaf(py, bu[c], fmaf(my, bl[c], aub[i]));
        }
        if (tid == 0) {
            float x = lb_row[N_IN];
            float y = ub_row[N_IN];
            alb[i] = fmaf(fmaxf(x, 0.f), blN, fmaf(fminf(x, 0.f), buN, alb[i]));
            aub[i] = fmaf(fmaxf(y, 0.f), buN, fmaf(fminf(y, 0.f), blN, aub[i]));
        }
        lb_row += NCOLS; ub_row += NCOLS; olb_row += NCOLS; oub_row += NCOLS;
    }

    // wave butterfly per row, then cross-wave combine in LDS, one barrier
#pragma unroll
    for (int i = 0; i < RPB; ++i) {
        for (int o = 32; o > 0; o >>= 1) {
            alb[i] += __shfl_xor(alb[i], o, 64);
            aub[i] += __shfl_xor(aub[i], o, 64);
        }
    }
    __shared__ float redLB[BLK / 64][RPB];
    __shared__ float redUB[BLK / 64][RPB];
    const int wave = tid >> 6;
    if ((tid & 63) == 0) {
#pragma unroll
        for (int i = 0; i < RPB; ++i) {
            redLB[wave][i] = alb[i];
            redUB[wave][i] = aub[i];
        }
    }
    __syncthreads();
    if (tid < 2 * RPB) {           // 16 finalizer threads: (row, which)
        const int i = tid >> 1;
        const int isUB = tid & 1;
        float s = 0.f;
#pragma unroll
        for (int w = 0; w < BLK / 64; ++w)
            s += isUB ? redUB[w][i] : redLB[w][i];
        size_t off = (size_t)(rowBase + i) * NCOLS + N_IN;
        if (isUB) off += (size_t)NROWS * NCOLS;
        out[off] = s;
    }
}

extern "C" void kernel_launch(void* const* d_in, const int* in_sizes, int n_in,
                              void* d_out, int out_size, void* d_ws, size_t ws_size,
                              hipStream_t stream) {
    const float* lb   = (const float*)d_in[0];
    const float* ub   = (const float*)d_in[1];
    const float* w_lb = (const float*)d_in[2];
    const float* w_ub = (const float*)d_in[3];
    float* out = (float*)d_out;
    float* ws  = (float*)d_ws;   // needs 4*PAD*4 = 65,664 bytes

    extract_scales<<<(NCOLS + 255) / 256, 256, 0, stream>>>(w_lb, w_ub, ws);
    backsub_rows<<<NROWS / RPB, BLK, 0, stream>>>(lb, ub, ws, out);
}